// Round 1
// baseline (1934.018 us; speedup 1.0000x reference)
//
#include <hip/hip_runtime.h>

// Problem constants (from reference)
#define NA 1024          // atoms
#define NC 80            // feats c
#define NI 48            // irreps
#define PQ (NI*NI)       // 2304
#define M3 (PQ*NI)       // 110592 rows of U3 viewed as [M3, K3]
#define K3 1270
#define K2 24
#define K1 3

// ---------------------------------------------------------------------------
// Kernel A: UW3t[c][pqi] = sum_k U3[pqi][k] * W3[k][c]
// GEMM M=110592, K=1270, N=80. Block tile 64(M) x 80(N), KC=32.
// 256 threads: compute mapping tr=t>>4 (4 rows each), tc=t&15 (5 cols: tc+16j).
// Output staged via LDS for coalesced [c][m] stores.
// ---------------------------------------------------------------------------
__global__ __launch_bounds__(256) void k_uw3(const float* __restrict__ U3,
                                             const float* __restrict__ W3,
                                             float* __restrict__ UW3t) {
    __shared__ float As[32][64];      // [kk][m]
    __shared__ float Bs[32][80];      // [kk][c]
    __shared__ float Os[80 * 65];     // [c][m] staging, padded 64->65

    const int t  = threadIdx.x;
    const int m0 = blockIdx.x * 64;

    const int tr = t >> 4;            // 0..15 -> rows tr*4 .. tr*4+3
    const int tc = t & 15;            // cols tc + 16*j, j=0..4

    float acc[4][5];
#pragma unroll
    for (int r = 0; r < 4; ++r)
#pragma unroll
        for (int j = 0; j < 5; ++j) acc[r][j] = 0.f;

    const int lm = t & 63;            // load: row within tile (conflict-free LDS write)
    const int lk = t >> 6;            // 0..3 -> k-subchunk of 8

    for (int k0 = 0; k0 < K3; k0 += 32) {
        // Load A tile: 64 rows x 32 k. Each thread 8 scalars along k of one row.
#pragma unroll
        for (int j = 0; j < 8; ++j) {
            int kk = lk * 8 + j;
            int k  = k0 + kk;
            As[kk][lm] = (k < K3) ? U3[(size_t)(m0 + lm) * K3 + k] : 0.f;
        }
        // Load B tile: 32 x 80 = 2560 floats, 10 per thread, coalesced.
#pragma unroll
        for (int u = 0; u < 10; ++u) {
            int f  = t + 256 * u;
            int kk = f / 80;
            int cc = f - kk * 80;
            int k  = k0 + kk;
            Bs[kk][cc] = (k < K3) ? W3[(size_t)k * NC + cc] : 0.f;
        }
        __syncthreads();
#pragma unroll
        for (int kk = 0; kk < 32; ++kk) {
            float4 a = *(const float4*)&As[kk][tr * 4];
#pragma unroll
            for (int j = 0; j < 5; ++j) {
                float b = Bs[kk][tc + 16 * j];
                acc[0][j] += a.x * b;
                acc[1][j] += a.y * b;
                acc[2][j] += a.z * b;
                acc[3][j] += a.w * b;
            }
        }
        __syncthreads();
    }

    // Stage to LDS in [c][m] layout, then coalesced store.
#pragma unroll
    for (int j = 0; j < 5; ++j) {
        int cc = tc + 16 * j;
#pragma unroll
        for (int r = 0; r < 4; ++r) Os[cc * 65 + tr * 4 + r] = acc[r][j];
    }
    __syncthreads();
#pragma unroll
    for (int u = 0; u < 20; ++u) {
        int f  = t + 256 * u;       // 0..5119
        int cc = f >> 6;
        int mm = f & 63;
        UW3t[(size_t)cc * M3 + m0 + mm] = Os[cc * 65 + mm];
    }
}

// ---------------------------------------------------------------------------
// Kernel C: c2t[c][pq] = sum_k U2[pq][k] * W2[k][c]   (tiny)
// ---------------------------------------------------------------------------
__global__ __launch_bounds__(256) void k_c2t(const float* __restrict__ U2,
                                             const float* __restrict__ W2,
                                             float* __restrict__ c2t) {
    int idx = blockIdx.x * 256 + threadIdx.x;   // c*PQ + pq
    if (idx >= NC * PQ) return;
    int c  = idx / PQ;
    int pq = idx - c * PQ;
    float s = 0.f;
#pragma unroll
    for (int k = 0; k < K2; ++k) s += U2[pq * K2 + k] * W2[k * NC + c];
    c2t[idx] = s;
}

// ---------------------------------------------------------------------------
// Kernel B: per (c, n-block of 64):
//   out[n,c] = sum_pq (sum_i T_c[pq][i] v[n][i] + c2t[c][pq]) * v_p * v_q
//            + sum_p c1[c][p] v[n][p]
// Tiles pq in chunks of 64. Thread reg-tile 4n x 4pq, K=48 via float4.
// LDS rows padded 48->52 dwords: 16-lane b128 reads at bank stride 20 mod 32
// -> 2-way aliasing only (free, m136).
// ---------------------------------------------------------------------------
__global__ __launch_bounds__(256) void k_main(const float* __restrict__ nf,
                                              const float* __restrict__ UW3t,
                                              const float* __restrict__ c2t,
                                              const float* __restrict__ U1,
                                              const float* __restrict__ W1,
                                              float* __restrict__ out) {
    __shared__ float Vs[64 * 52];
    __shared__ float Ts[64 * 52];
    __shared__ float c2s[64];
    __shared__ float c1s[NI];
    __shared__ float red[64 * 17];

    const int t  = threadIdx.x;
    const int c  = blockIdx.x >> 4;     // 0..79
    const int nb = blockIdx.x & 15;     // 0..15
    const int n0 = nb * 64;

    // Load V block: 64 rows x 48 floats, 3 float4 per thread, coalesced per row.
#pragma unroll
    for (int u = 0; u < 3; ++u) {
        int f   = t + 256 * u;          // 0..767
        int row = f / 12;
        int seg = f - row * 12;
        float4 v = *(const float4*)&nf[((size_t)(n0 + row) * NC + c) * NI + seg * 4];
        *(float4*)&Vs[row * 52 + seg * 4] = v;
    }
    // c1s[p] = sum_k U1[p][k] * W1[k][c]
    if (t < NI) {
        float s = 0.f;
#pragma unroll
        for (int k = 0; k < K1; ++k) s += U1[t * K1 + k] * W1[k * NC + c];
        c1s[t] = s;
    }

    const int tn = t & 15;              // n = 16*a + tn
    const int tq = t >> 4;              // pq_local = 16*b + tq
    float oacc[4] = {0.f, 0.f, 0.f, 0.f};
    const float* Tc = UW3t + (size_t)c * M3;

    for (int tile = 0; tile < PQ / 64; ++tile) {
        const int pq0 = tile * 64;
        __syncthreads();                // protect Ts (and Vs on first iter)
        // Load T tile: 64x48 floats, fully contiguous in UW3t[c].
#pragma unroll
        for (int u = 0; u < 3; ++u) {
            int f   = t + 256 * u;
            int row = f / 12;
            int seg = f - row * 12;
            float4 v = *(const float4*)&Tc[(size_t)pq0 * NI + f * 4];
            *(float4*)&Ts[row * 52 + seg * 4] = v;
        }
        if (t < 64) c2s[t] = c2t[(size_t)c * PQ + pq0 + t];
        __syncthreads();

        // Y[a][b] = sum_i V[16a+tn][i] * T[16b+tq][i]
        float y[4][4] = {{0.f,0.f,0.f,0.f},{0.f,0.f,0.f,0.f},
                         {0.f,0.f,0.f,0.f},{0.f,0.f,0.f,0.f}};
#pragma unroll
        for (int i4 = 0; i4 < 12; ++i4) {
            float4 va[4], tb[4];
#pragma unroll
            for (int r = 0; r < 4; ++r)
                va[r] = *(const float4*)&Vs[(16 * r + tn) * 52 + 4 * i4];
#pragma unroll
            for (int r = 0; r < 4; ++r)
                tb[r] = *(const float4*)&Ts[(16 * r + tq) * 52 + 4 * i4];
#pragma unroll
            for (int a = 0; a < 4; ++a)
#pragma unroll
                for (int b = 0; b < 4; ++b)
                    y[a][b] += va[a].x * tb[b].x + va[a].y * tb[b].y +
                               va[a].z * tb[b].z + va[a].w * tb[b].w;
        }
        // Fused contraction: oacc[a] += (Y + c2t) * v_p * v_q
#pragma unroll
        for (int b = 0; b < 4; ++b) {
            int pql = 16 * b + tq;
            int pqg = pq0 + pql;
            int p   = pqg / NI;
            int q   = pqg - p * NI;
            float cv = c2s[pql];
#pragma unroll
            for (int a = 0; a < 4; ++a) {
                int n = 16 * a + tn;
                oacc[a] += (y[a][b] + cv) * Vs[n * 52 + p] * Vs[n * 52 + q];
            }
        }
    }

    // Block reduction over the 16 pq-thread-groups.
    __syncthreads();
#pragma unroll
    for (int a = 0; a < 4; ++a) red[(16 * a + tn) * 17 + tq] = oacc[a];
    __syncthreads();
    if (t < 64) {
        float s = 0.f;
#pragma unroll
        for (int j = 0; j < 16; ++j) s += red[t * 17 + j];
#pragma unroll
        for (int p = 0; p < NI; ++p) s += c1s[p] * Vs[t * 52 + p];
        out[(size_t)(n0 + t) * NC + c] = s;
    }
}

// ---------------------------------------------------------------------------
extern "C" void kernel_launch(void* const* d_in, const int* in_sizes, int n_in,
                              void* d_out, int out_size, void* d_ws, size_t ws_size,
                              hipStream_t stream) {
    const float* nf = (const float*)d_in[0];
    const float* U3 = (const float*)d_in[1];
    const float* U2 = (const float*)d_in[2];
    const float* U1 = (const float*)d_in[3];
    const float* W3 = (const float*)d_in[4];
    const float* W2 = (const float*)d_in[5];
    const float* W1 = (const float*)d_in[6];
    float* out = (float*)d_out;

    float* UW3t = (float*)d_ws;                       // NC*M3 floats = 35.4 MB
    float* c2tw = UW3t + (size_t)NC * M3;             // NC*PQ floats = 0.74 MB

    k_uw3 <<<M3 / 64,              256, 0, stream>>>(U3, W3, UW3t);
    k_c2t <<<(NC * PQ + 255) / 256, 256, 0, stream>>>(U2, W2, c2tw);
    k_main<<<NC * 16,              256, 0, stream>>>(nf, UW3t, c2tw, U1, W1, out);
}

// Round 2
// 1267.818 us; speedup vs baseline: 1.5255x; 1.5255x over previous
//
#include <hip/hip_runtime.h>
#include <hip/hip_bf16.h>

// Problem constants
#define NA 1024          // atoms
#define NC 80            // feats c
#define NI 48            // irreps
#define PQ (NI*NI)       // 2304
#define M3 (PQ*NI)       // 110592
#define K3 1270
#define K3P 1280         // K3 padded to 32
#define K2 24
#define K1 3

typedef __attribute__((ext_vector_type(8))) short bf16x8;  // 8 bf16 = 4 VGPRs
typedef __attribute__((ext_vector_type(4))) float f32x4;

union BFPack { bf16x8 v; __hip_bfloat162 h[4]; };

__device__ __forceinline__ bf16x8 pack8(float a, float b, float c, float d,
                                        float e, float f, float g, float h) {
    BFPack u;
    u.h[0] = __float22bfloat162_rn(float2{a, b});
    u.h[1] = __float22bfloat162_rn(float2{c, d});
    u.h[2] = __float22bfloat162_rn(float2{e, f});
    u.h[3] = __float22bfloat162_rn(float2{g, h});
    return u.v;
}

// ---------------------------------------------------------------------------
// W3bt[c][k] = bf16(W3[k][c]), k padded 1270->1280 with zeros. 200 KB, L2-hot.
// ---------------------------------------------------------------------------
__global__ __launch_bounds__(256) void k_w3t(const float* __restrict__ W3,
                                             __hip_bfloat16* __restrict__ W3bt) {
    int c = blockIdx.x;
    for (int k = threadIdx.x; k < K3P; k += 256) {
        float v = (k < K3) ? W3[(size_t)k * NC + c] : 0.f;
        W3bt[(size_t)c * K3P + k] = __float2bfloat16(v);
    }
}

// ---------------------------------------------------------------------------
// Kernel A (MFMA): UW3t[c][m] = sum_k U3[m][k] * W3[k][c]
// M=110592, N=80, K=1270. 4 waves/block, wave owns 16 m-rows x all 80 c.
// A frag: lane holds A[m=lane&15][k=quad*8+j] -> two float2x2 loads from U3
//   (row stride 5080 B is 8B-aligned, so float2 is safe; float4 is not).
// B frag: lane holds B[k=quad*8+j][c=lane&15] -> one 16B load from W3bt.
// D frag: D[row=quad*4+r][col=lane&15]. No LDS, no barriers.
// ---------------------------------------------------------------------------
__global__ __launch_bounds__(256) void k_uw3(const float* __restrict__ U3,
                                             const __hip_bfloat16* __restrict__ W3bt,
                                             float* __restrict__ UW3t) {
    const int t    = threadIdx.x;
    const int wave = t >> 6;
    const int lane = t & 63;
    const int row  = lane & 15;     // A: m_local / B: c_local / D: col
    const int quad = lane >> 4;

    const int m_base = blockIdx.x * 64 + wave * 16;
    const float* __restrict__ arow = U3 + (size_t)(m_base + row) * K3;

    f32x4 acc[5];
#pragma unroll
    for (int j = 0; j < 5; ++j) acc[j] = (f32x4)(0.f);

    const int kq = quad * 8;

    for (int k0 = 0; k0 < K3 - 31; k0 += 32) {   // k0 = 0..1216 (38 full iters)
        const int kb = k0 + kq;
        const float2* a2 = (const float2*)(arow + kb);   // 8B-aligned always
        float2 p0 = a2[0], p1 = a2[1], p2 = a2[2], p3 = a2[3];
        bf16x8 af = pack8(p0.x, p0.y, p1.x, p1.y, p2.x, p2.y, p3.x, p3.y);
#pragma unroll
        for (int j = 0; j < 5; ++j) {
            bf16x8 bf = *(const bf16x8*)(W3bt + (size_t)(16 * j + row) * K3P + kb);
            acc[j] = __builtin_amdgcn_mfma_f32_16x16x32_bf16(af, bf, acc[j], 0, 0, 0);
        }
    }
    {   // peel k0 = 1248: k in [1248,1280), valid k < 1270
        const int kb = 1248 + kq;
        float av[8];
#pragma unroll
        for (int j = 0; j < 8; ++j) {
            int k = kb + j;
            av[j] = (k < K3) ? arow[k] : 0.f;
        }
        bf16x8 af = pack8(av[0], av[1], av[2], av[3], av[4], av[5], av[6], av[7]);
#pragma unroll
        for (int j = 0; j < 5; ++j) {
            bf16x8 bf = *(const bf16x8*)(W3bt + (size_t)(16 * j + row) * K3P + kb);
            acc[j] = __builtin_amdgcn_mfma_f32_16x16x32_bf16(af, bf, acc[j], 0, 0, 0);
        }
    }

    // Store: D[row'=quad*4+r][col=lane&15]; UW3t layout [c][m]. 16B-aligned.
#pragma unroll
    for (int j = 0; j < 5; ++j) {
        int c = 16 * j + row;
        size_t o = (size_t)c * M3 + m_base + quad * 4;
        *(f32x4*)&UW3t[o] = acc[j];
    }
}

// ---------------------------------------------------------------------------
// c2t[c][pq] = sum_k U2[pq][k] * W2[k][c]   (tiny)
// ---------------------------------------------------------------------------
__global__ __launch_bounds__(256) void k_c2t(const float* __restrict__ U2,
                                             const float* __restrict__ W2,
                                             float* __restrict__ c2t) {
    int idx = blockIdx.x * 256 + threadIdx.x;
    if (idx >= NC * PQ) return;
    int c  = idx / PQ;
    int pq = idx - c * PQ;
    float s = 0.f;
#pragma unroll
    for (int k = 0; k < K2; ++k) s += U2[pq * K2 + k] * W2[k * NC + c];
    c2t[idx] = s;
}

// ---------------------------------------------------------------------------
// Kernel B: unchanged math, + register prefetch of next T tile so the global
// load latency overlaps the tile's compute instead of stalling at the barrier.
// ---------------------------------------------------------------------------
__global__ __launch_bounds__(256) void k_main(const float* __restrict__ nf,
                                              const float* __restrict__ UW3t,
                                              const float* __restrict__ c2t,
                                              const float* __restrict__ U1,
                                              const float* __restrict__ W1,
                                              float* __restrict__ out) {
    __shared__ float Vs[64 * 52];
    __shared__ float Ts[64 * 52];
    __shared__ float c2s[64];
    __shared__ float c1s[NI];
    __shared__ float red[64 * 17];

    const int t  = threadIdx.x;
    const int c  = blockIdx.x >> 4;
    const int nb = blockIdx.x & 15;
    const int n0 = nb * 64;

#pragma unroll
    for (int u = 0; u < 3; ++u) {
        int f   = t + 256 * u;
        int row = f / 12;
        int seg = f - row * 12;
        float4 v = *(const float4*)&nf[((size_t)(n0 + row) * NC + c) * NI + seg * 4];
        *(float4*)&Vs[row * 52 + seg * 4] = v;
    }
    if (t < NI) {
        float s = 0.f;
#pragma unroll
        for (int k = 0; k < K1; ++k) s += U1[t * K1 + k] * W1[k * NC + c];
        c1s[t] = s;
    }

    const int tn = t & 15;
    const int tq = t >> 4;
    float oacc[4] = {0.f, 0.f, 0.f, 0.f};
    const float* Tc = UW3t + (size_t)c * M3;

    // prefetch tile 0
    float4 pre[3];
    {
        int row0 = t / 12;      // unused decomposition; loads are flat f*4
#pragma unroll
        for (int u = 0; u < 3; ++u) {
            int f = t + 256 * u;
            pre[u] = *(const float4*)&Tc[(size_t)f * 4];
        }
        (void)row0;
    }

    for (int tile = 0; tile < PQ / 64; ++tile) {
        const int pq0 = tile * 64;
        __syncthreads();                // previous compute done; Vs ready (iter0)
#pragma unroll
        for (int u = 0; u < 3; ++u) {
            int f   = t + 256 * u;
            int row = f / 12;
            int seg = f - row * 12;
            *(float4*)&Ts[row * 52 + seg * 4] = pre[u];
        }
        if (t < 64) c2s[t] = c2t[(size_t)c * PQ + pq0 + t];
        __syncthreads();

        // issue next tile's loads now; they complete during compute
        {
            int nt = (tile + 1 < PQ / 64) ? tile + 1 : tile;   // clamped, in-bounds
#pragma unroll
            for (int u = 0; u < 3; ++u) {
                int f = t + 256 * u;
                pre[u] = *(const float4*)&Tc[(size_t)nt * 64 * NI + f * 4];
            }
        }

        float y[4][4] = {{0.f,0.f,0.f,0.f},{0.f,0.f,0.f,0.f},
                         {0.f,0.f,0.f,0.f},{0.f,0.f,0.f,0.f}};
#pragma unroll
        for (int i4 = 0; i4 < 12; ++i4) {
            float4 va[4], tb[4];
#pragma unroll
            for (int r = 0; r < 4; ++r)
                va[r] = *(const float4*)&Vs[(16 * r + tn) * 52 + 4 * i4];
#pragma unroll
            for (int r = 0; r < 4; ++r)
                tb[r] = *(const float4*)&Ts[(16 * r + tq) * 52 + 4 * i4];
#pragma unroll
            for (int a = 0; a < 4; ++a)
#pragma unroll
                for (int b = 0; b < 4; ++b)
                    y[a][b] += va[a].x * tb[b].x + va[a].y * tb[b].y +
                               va[a].z * tb[b].z + va[a].w * tb[b].w;
        }
#pragma unroll
        for (int b = 0; b < 4; ++b) {
            int pql = 16 * b + tq;
            int pqg = pq0 + pql;
            int p   = pqg / NI;
            int q   = pqg - p * NI;
            float cv = c2s[pql];
#pragma unroll
            for (int a = 0; a < 4; ++a) {
                int n = 16 * a + tn;
                oacc[a] += (y[a][b] + cv) * Vs[n * 52 + p] * Vs[n * 52 + q];
            }
        }
    }

    __syncthreads();
#pragma unroll
    for (int a = 0; a < 4; ++a) red[(16 * a + tn) * 17 + tq] = oacc[a];
    __syncthreads();
    if (t < 64) {
        float s = 0.f;
#pragma unroll
        for (int j = 0; j < 16; ++j) s += red[t * 17 + j];
#pragma unroll
        for (int p = 0; p < NI; ++p) s += c1s[p] * Vs[t * 52 + p];
        out[(size_t)(n0 + t) * NC + c] = s;
    }
}

// ---------------------------------------------------------------------------
extern "C" void kernel_launch(void* const* d_in, const int* in_sizes, int n_in,
                              void* d_out, int out_size, void* d_ws, size_t ws_size,
                              hipStream_t stream) {
    const float* nf = (const float*)d_in[0];
    const float* U3 = (const float*)d_in[1];
    const float* U2 = (const float*)d_in[2];
    const float* U1 = (const float*)d_in[3];
    const float* W3 = (const float*)d_in[4];
    const float* W2 = (const float*)d_in[5];
    const float* W1 = (const float*)d_in[6];
    float* out = (float*)d_out;

    float* UW3t = (float*)d_ws;                       // NC*M3 floats = 35.4 MB
    float* c2tw = UW3t + (size_t)NC * M3;             // NC*PQ floats = 0.74 MB
    // W3bt aliases the c2t buffer: used only by k_uw3, which completes before
    // k_c2t overwrites the region (same-stream ordering). 200 KB < 737 KB.
    __hip_bfloat16* W3bt = (__hip_bfloat16*)c2tw;

    k_w3t <<<NC,                    256, 0, stream>>>(W3, W3bt);
    k_uw3 <<<M3 / 64,               256, 0, stream>>>(U3, W3bt, UW3t);
    k_c2t <<<(NC * PQ + 255) / 256, 256, 0, stream>>>(U2, W2, c2tw);
    k_main<<<NC * 16,               256, 0, stream>>>(nf, UW3t, c2tw, U1, W1, out);
}